// Round 16
// baseline (2481.596 us; speedup 1.0000x reference)
//
#include <hip/hip_runtime.h>
#include <hip/hip_bf16.h>

typedef __hip_bfloat16 bf16;

// Problem dims
#define B_    16
#define T_    128
#define S_    192
#define H_    768
#define G4_   3072      // 4*H
#define V_    30522
#define AV_   200
#define L_    191       // L_SRC-1
#define TM1_  127       // T-1
#define R_    2032      // B*(T-1)
#define K5_   3840      // 5*H
#define NB_   48        // blocks per LSTM (persistent)
#define HSL_  16        // h-slice per block (768/48)
#define NCV_  96        // converter blocks appended to the LSTM grid

typedef short bf16x8_t __attribute__((ext_vector_type(8)));
typedef float f32x4_t  __attribute__((ext_vector_type(4)));

__device__ __forceinline__ float bf2f(bf16 v) { return __bfloat162float(v); }
__device__ __forceinline__ bf16  f2bf(float v) { return __float2bfloat16(v); }
__device__ __forceinline__ unsigned short f2us(float v) { bf16 h = f2bf(v); return *reinterpret_cast<unsigned short*>(&h); }
__device__ __forceinline__ float uslo(unsigned u) { union { unsigned i; float f; } x; x.i = u << 16; return x.f; }
__device__ __forceinline__ float ushi(unsigned u) { union { unsigned i; float f; } x; x.i = u & 0xffff0000u; return x.f; }
__device__ __forceinline__ float us2f(unsigned short u) { union { unsigned i; float f; } x; x.i = ((unsigned)u) << 16; return x.f; }
__device__ __forceinline__ float sigm(float x) { return 1.0f / (1.0f + expf(-x)); }

// async global->LDS, 16B per lane; LDS dest = uniform base + lane*16
#define GLDS(gptr, lptr) \
    __builtin_amdgcn_global_load_lds((const __attribute__((address_space(1))) void*)(gptr), \
                                     (__attribute__((address_space(3))) void*)(lptr), 16, 0, 0)

// ---------------------------------------------------------------------------
// MFMA GEMM (bf16 x bf16): C[M,N] = act( A[M,K] * W[N,K]^T + bias1 + bias2 )
// 128x128 tile, 256 threads (4 waves 2x2), K-step 64, global_load_lds staging
// with XOR chunk swizzle. rowdiv>0 remaps A rows r -> r + r/rowdiv + 1;
// gidx!=null maps A row r -> gidx[r]. K % 64 == 0.
// ---------------------------------------------------------------------------
__global__ __launch_bounds__(256) void gemm_mfma(
    const bf16* __restrict__ A, const bf16* __restrict__ W,
    const float* __restrict__ bias1, const float* __restrict__ bias2,
    bf16* __restrict__ Ch, float* __restrict__ Cf,
    int M, int N, int K, int act, int rowdiv, int lda,
    const int* __restrict__ gidx)
{
    __shared__ short As[128 * 64];   // 16 KB, unpadded
    __shared__ short Ws[128 * 64];
    const int tid = threadIdx.x;
    const int wave = tid >> 6, lane = tid & 63;
    const int mw = (wave >> 1) * 64, nw = (wave & 1) * 64;
    const int bm = blockIdx.x * 128, bn = blockIdx.y * 128;

    const int schunk = (lane & 7) ^ (lane >> 3);

    const bf16* aSrc[4];
    const bf16* wSrc[4];
#pragma unroll
    for (int j = 0; j < 4; ++j) {
        const int idx = wave * 4 + j;
        const int srow = idx * 8 + (lane >> 3);
        int ga = bm + srow; if (ga > M - 1) ga = M - 1;
        int ra;
        if (gidx) ra = gidx[ga];
        else ra = (rowdiv > 0) ? (ga + ga / rowdiv + 1) : ga;
        aSrc[j] = A + (size_t)ra * lda + schunk * 8;
        int gw = bn + srow; if (gw > N - 1) gw = N - 1;
        wSrc[j] = W + (size_t)gw * K + schunk * 8;
    }

    f32x4_t acc[4][4];
#pragma unroll
    for (int mi = 0; mi < 4; ++mi)
#pragma unroll
        for (int ni = 0; ni < 4; ++ni) acc[mi][ni] = (f32x4_t){0.f, 0.f, 0.f, 0.f};

    const int fr = lane & 15;
    const int fr7 = fr & 7;
    const int cq = lane >> 4;

    for (int k0 = 0; k0 < K; k0 += 64) {
#pragma unroll
        for (int j = 0; j < 4; ++j) {
            const int idx = wave * 4 + j;
            GLDS(aSrc[j] + k0, &As[idx * 512]);
            GLDS(wSrc[j] + k0, &Ws[idx * 512]);
        }
        __syncthreads();
#pragma unroll
        for (int half = 0; half < 2; ++half) {
            const int gc = half * 4 + cq;
            const int lc = (gc ^ fr7) * 8;
            bf16x8_t af[4], wf[4];
#pragma unroll
            for (int i = 0; i < 4; ++i)
                af[i] = *(const bf16x8_t*)&As[(mw + i * 16 + fr) * 64 + lc];
#pragma unroll
            for (int i = 0; i < 4; ++i)
                wf[i] = *(const bf16x8_t*)&Ws[(nw + i * 16 + fr) * 64 + lc];
#pragma unroll
            for (int mi = 0; mi < 4; ++mi)
#pragma unroll
                for (int ni = 0; ni < 4; ++ni)
                    acc[mi][ni] = __builtin_amdgcn_mfma_f32_16x16x32_bf16(af[mi], wf[ni], acc[mi][ni], 0, 0, 0);
        }
        __syncthreads();
    }

    const int cl = lane & 15;
    const int rg = (lane >> 4) * 4;
#pragma unroll
    for (int mi = 0; mi < 4; ++mi) {
#pragma unroll
        for (int ni = 0; ni < 4; ++ni) {
            const int col = bn + nw + ni * 16 + cl;
            if (col >= N) continue;
#pragma unroll
            for (int j = 0; j < 4; ++j) {
                const int row = bm + mw + mi * 16 + rg + j;
                if (row >= M) continue;
                float v = acc[mi][ni][j];
                if (bias1) v += bias1[col];
                if (bias2) v += bias2[col];
                if (act == 1) v = tanhf(v);
                if (Ch) Ch[(size_t)row * N + col] = f2bf(v);
                else    Cf[(size_t)row * N + col] = v;
            }
        }
    }
}

// ---------------------------------------------------------------------------
// MFMA GEMM, 256-row M-tile variant: two 128-row strips share one staged W
// tile (halves W panel traffic). LDS 48 KB; same fragment math per strip.
// ---------------------------------------------------------------------------
__global__ __launch_bounds__(256) void gemm_mfma2(
    const bf16* __restrict__ A, const bf16* __restrict__ W,
    const float* __restrict__ bias1, const float* __restrict__ bias2,
    bf16* __restrict__ Ch, float* __restrict__ Cf,
    int M, int N, int K, int act, int lda)
{
    __shared__ short As[2][128 * 64];   // 32 KB
    __shared__ short Ws[128 * 64];      // 16 KB
    const int tid = threadIdx.x;
    const int wave = tid >> 6, lane = tid & 63;
    const int mw = (wave >> 1) * 64, nw = (wave & 1) * 64;
    const int bm = blockIdx.x * 256, bn = blockIdx.y * 128;

    const int schunk = (lane & 7) ^ (lane >> 3);

    const bf16* aSrc[2][4];
    const bf16* wSrc[4];
#pragma unroll
    for (int j = 0; j < 4; ++j) {
        const int idx = wave * 4 + j;
        const int srow = idx * 8 + (lane >> 3);
#pragma unroll
        for (int hm = 0; hm < 2; ++hm) {
            int ga = bm + hm * 128 + srow; if (ga > M - 1) ga = M - 1;
            aSrc[hm][j] = A + (size_t)ga * lda + schunk * 8;
        }
        int gw = bn + srow; if (gw > N - 1) gw = N - 1;
        wSrc[j] = W + (size_t)gw * K + schunk * 8;
    }

    f32x4_t acc[2][4][4];
#pragma unroll
    for (int hm = 0; hm < 2; ++hm)
#pragma unroll
        for (int mi = 0; mi < 4; ++mi)
#pragma unroll
            for (int ni = 0; ni < 4; ++ni) acc[hm][mi][ni] = (f32x4_t){0.f, 0.f, 0.f, 0.f};

    const int fr = lane & 15;
    const int fr7 = fr & 7;
    const int cq = lane >> 4;

    for (int k0 = 0; k0 < K; k0 += 64) {
#pragma unroll
        for (int j = 0; j < 4; ++j) {
            const int idx = wave * 4 + j;
            GLDS(aSrc[0][j] + k0, &As[0][idx * 512]);
            GLDS(aSrc[1][j] + k0, &As[1][idx * 512]);
            GLDS(wSrc[j] + k0,    &Ws[idx * 512]);
        }
        __syncthreads();
#pragma unroll
        for (int half = 0; half < 2; ++half) {
            const int gc = half * 4 + cq;
            const int lc = (gc ^ fr7) * 8;
            bf16x8_t wf[4];
#pragma unroll
            for (int i = 0; i < 4; ++i)
                wf[i] = *(const bf16x8_t*)&Ws[(nw + i * 16 + fr) * 64 + lc];
#pragma unroll
            for (int hm = 0; hm < 2; ++hm) {
                bf16x8_t af[4];
#pragma unroll
                for (int i = 0; i < 4; ++i)
                    af[i] = *(const bf16x8_t*)&As[hm][(mw + i * 16 + fr) * 64 + lc];
#pragma unroll
                for (int mi = 0; mi < 4; ++mi)
#pragma unroll
                    for (int ni = 0; ni < 4; ++ni)
                        acc[hm][mi][ni] = __builtin_amdgcn_mfma_f32_16x16x32_bf16(af[mi], wf[ni], acc[hm][mi][ni], 0, 0, 0);
            }
        }
        __syncthreads();
    }

    const int cl = lane & 15;
    const int rg = (lane >> 4) * 4;
#pragma unroll
    for (int hm = 0; hm < 2; ++hm) {
#pragma unroll
        for (int mi = 0; mi < 4; ++mi) {
#pragma unroll
            for (int ni = 0; ni < 4; ++ni) {
                const int col = bn + nw + ni * 16 + cl;
                if (col >= N) continue;
#pragma unroll
                for (int j = 0; j < 4; ++j) {
                    const int row = bm + hm * 128 + mw + mi * 16 + rg + j;
                    if (row >= M) continue;
                    float v = acc[hm][mi][ni][j];
                    if (bias1) v += bias1[col];
                    if (bias2) v += bias2[col];
                    if (act == 1) v = tanhf(v);
                    if (Ch) Ch[(size_t)row * N + col] = f2bf(v);
                    else    Cf[(size_t)row * N + col] = v;
                }
            }
        }
    }
}

// ---------------------------------------------------------------------------
// Batch f32 -> bf16 conversion of 9 matrices
// ---------------------------------------------------------------------------
struct ConvJobs {
    const float* src[9];
    bf16* dst[9];
    int n4[9];
};
__global__ void conv_many_kernel(ConvJobs jobs)
{
    const int w = blockIdx.y;
    const int i = blockIdx.x * 256 + threadIdx.x;
    if (i >= jobs.n4[w]) return;
    const float* s = jobs.src[w];
    bf16* d = jobs.dst[w];
    float4 v = *(const float4*)(s + (size_t)i * 4);
    ushort4 o;
    o.x = f2us(v.x); o.y = f2us(v.y); o.z = f2us(v.z); o.w = f2us(v.w);
    *(ushort4*)(d + (size_t)i * 4) = o;
}

// ---------------------------------------------------------------------------
// Persistent cooperative LSTM + W_out converter worker blocks (round-12 logic).
// ---------------------------------------------------------------------------
__global__ __launch_bounds__(256) void lstm_mfma_kernel(
    const bf16* __restrict__ pxe, const bf16* __restrict__ pxa, const bf16* __restrict__ pxw,
    const float* __restrict__ We, const float* __restrict__ Wa, const float* __restrict__ Ww,
    bf16* __restrict__ oute, bf16* __restrict__ outa, bf16* __restrict__ outw,
    unsigned short* __restrict__ hbuf, int* __restrict__ flags,
    const float* __restrict__ Wout, bf16* __restrict__ Wob)
{
    const int tid = threadIdx.x;

    if (blockIdx.x >= 3 * NB_) {
        const int wid = blockIdx.x - 3 * NB_;
        const int n4 = V_ * H_ / 4;
        for (int i = wid * 256 + tid; i < n4; i += NCV_ * 256) {
            float4 v = *(const float4*)(Wout + (size_t)i * 4);
            ushort4 o;
            o.x = f2us(v.x); o.y = f2us(v.y); o.z = f2us(v.z); o.w = f2us(v.w);
            *(ushort4*)(Wob + (size_t)i * 4) = o;
        }
        return;
    }

    const int which = blockIdx.x / NB_;
    const int nb = blockIdx.x % NB_;
    const bf16* px; const float* W; bf16* out; int Tn;
    if (which == 0)      { px = pxe; W = We; out = oute; Tn = T_; }
    else if (which == 1) { px = pxa; W = Wa; out = outa; Tn = T_; }
    else                 { px = pxw; W = Ww; out = outw; Tn = S_; }
    unsigned short* hG = hbuf + (size_t)which * (2 * B_ * H_);
    int* flg = flags + which * 64;

    const int wv = tid >> 6;
    const int lane = tid & 63;
    const int so = nb * HSL_;

    __shared__ unsigned short hL[16][776];
    __shared__ float gS[4][16][17];
    __shared__ unsigned short oring[8][16][16];

    bf16x8_t Afrag[24];
    {
        const int m = lane & 15;
        const int kb8 = (lane >> 4) * 8;
        const float* wrow = W + (size_t)(wv * H_ + so + m) * H_ + kb8;
#pragma unroll
        for (int kb = 0; kb < 24; ++kb) {
            float4 f0 = *(const float4*)(wrow + kb * 32);
            float4 f1 = *(const float4*)(wrow + kb * 32 + 4);
            bf16x8_t a;
            a[0] = (short)f2us(f0.x); a[1] = (short)f2us(f0.y);
            a[2] = (short)f2us(f0.z); a[3] = (short)f2us(f0.w);
            a[4] = (short)f2us(f1.x); a[5] = (short)f2us(f1.y);
            a[6] = (short)f2us(f1.z); a[7] = (short)f2us(f1.w);
            Afrag[kb] = a;
        }
    }

    for (int i = tid; i < 16 * 776; i += 256) ((unsigned short*)hL)[i] = 0;

    const int cb = tid >> 4;
    const int chl = tid & 15;
    float c = 0.f;

    const int bn = lane & 15;
    const int bk = (lane >> 4) * 8;

    unsigned short pxr0, pxr1, pxr2, pxr3;
    {
        const bf16* q = px + ((size_t)cb * Tn + 0) * G4_ + so + chl;
        pxr0 = *(const unsigned short*)(q);
        pxr1 = *(const unsigned short*)(q + H_);
        pxr2 = *(const unsigned short*)(q + 2 * H_);
        pxr3 = *(const unsigned short*)(q + 3 * H_);
    }

    int cur = 0;
    for (int step = 0; step < Tn; ++step) {
        if (step > 0) {
            const unsigned long long* hsrc =
                (const unsigned long long*)(hG + (size_t)cur * (B_ * H_));
            for (int i = tid; i < B_ * H_ / 4; i += 256) {
                const unsigned long long v =
                    __hip_atomic_load(hsrc + i, __ATOMIC_RELAXED, __HIP_MEMORY_SCOPE_AGENT);
                const int bb = i / (H_ / 4);
                const int cc = i - bb * (H_ / 4);
                ((unsigned long long*)&hL[bb][0])[cc] = v;
            }
        }
        __syncthreads();

        f32x4_t acc = {0.f, 0.f, 0.f, 0.f};
#pragma unroll
        for (int kb = 0; kb < 24; ++kb) {
            bf16x8_t bfr = *(const bf16x8_t*)&hL[bn][kb * 32 + bk];
            acc = __builtin_amdgcn_mfma_f32_16x16x32_bf16(Afrag[kb], bfr, acc, 0, 0, 0);
        }
        {
            const int m0 = (lane >> 4) * 4;
#pragma unroll
            for (int j = 0; j < 4; ++j) gS[wv][m0 + j][bn] = acc[j];
        }
        __syncthreads();

        {
            const float gi = gS[0][chl][cb] + us2f(pxr0);
            const float gf = gS[1][chl][cb] + us2f(pxr1);
            const float gg = gS[2][chl][cb] + us2f(pxr2);
            const float go = gS[3][chl][cb] + us2f(pxr3);
            const float cn = sigm(gf) * c + sigm(gi) * tanhf(gg);
            const float hn = sigm(go) * tanhf(cn);
            c = cn;
            oring[step & 7][cb][chl] = f2us(hn);
            __hip_atomic_store(&hG[(size_t)(cur ^ 1) * (B_ * H_) + cb * H_ + so + chl],
                               f2us(hn), __ATOMIC_RELAXED, __HIP_MEMORY_SCOPE_AGENT);
        }

        if (step + 1 < Tn) {
            __syncthreads();
            const int target = step + 1;
            if (tid == 0)
                __hip_atomic_store(&flg[nb], target, __ATOMIC_RELAXED, __HIP_MEMORY_SCOPE_AGENT);
            {
                const bf16* q = px + ((size_t)cb * Tn + target) * G4_ + so + chl;
                pxr0 = *(const unsigned short*)(q);
                pxr1 = *(const unsigned short*)(q + H_);
                pxr2 = *(const unsigned short*)(q + 2 * H_);
                pxr3 = *(const unsigned short*)(q + 3 * H_);
            }
            if ((step & 7) == 7) {
                const int base = step & ~7;
                for (int s2 = 0; s2 < 8; ++s2)
                    out[((size_t)cb * Tn + base + s2) * H_ + so + chl] =
                        *reinterpret_cast<const bf16*>(&oring[s2][cb][chl]);
            }
            if (lane < NB_) {
                long guard = 0;
                while (__hip_atomic_load(&flg[lane], __ATOMIC_RELAXED, __HIP_MEMORY_SCOPE_AGENT) < target) {
                    __builtin_amdgcn_s_sleep(1);
                    if (++guard > 50000000L) break;
                }
            }
        } else {
            const int base = step & ~7;
            const int cnt8 = (step & 7) + 1;
            for (int s2 = 0; s2 < cnt8; ++s2)
                out[((size_t)cb * Tn + base + s2) * H_ + so + chl] =
                    *reinterpret_cast<const bf16*>(&oring[s2][cb][chl]);
        }
        cur ^= 1;
    }
}

// ---------------------------------------------------------------------------
// Fused row gathers: out[r][:] = bf16(emb[ids[r]][:]) for 3 id arrays
// ---------------------------------------------------------------------------
__global__ void gather3_kernel(const int* __restrict__ ids_e, const int* __restrict__ ids_a,
                               const int* __restrict__ ids_w, const float* __restrict__ emb,
                               bf16* __restrict__ oe, bf16* __restrict__ oa,
                               bf16* __restrict__ ow)
{
    const int which = blockIdx.y;
    const int r = blockIdx.x;
    const int* ids; bf16* out; int nr;
    if (which == 0)      { ids = ids_e; out = oe; nr = B_ * T_; }
    else if (which == 1) { ids = ids_a; out = oa; nr = B_ * T_; }
    else                 { ids = ids_w; out = ow; nr = B_ * S_; }
    if (r >= nr) return;
    const float4* src = (const float4*)(emb + (size_t)ids[r] * H_);
    ushort4* dst = (ushort4*)(out + (size_t)r * H_);
    for (int h = threadIdx.x; h < H_ / 4; h += 256) {
        float4 v = src[h];
        ushort4 o;
        o.x = f2us(v.x); o.y = f2us(v.y); o.z = f2us(v.z); o.w = f2us(v.w);
        dst[h] = o;
    }
}

// ---------------------------------------------------------------------------
// Counters scan (+ cwrow[r] = b*S + ci[r])
// ---------------------------------------------------------------------------
__global__ void counters_kernel(const int* __restrict__ edits, const int* __restrict__ org,
                                int* __restrict__ cd, int* __restrict__ ci, int* __restrict__ ca,
                                int* __restrict__ cwrow)
{
    const int b = threadIdx.x;
    if (b >= B_) return;
    int vd = 0, vi = 0, va = 0;
    for (int t = 0; t < TM1_; ++t) {
        cd[b * TM1_ + t] = vd; ci[b * TM1_ + t] = vi; ca[b * TM1_ + t] = va;
        cwrow[b * TM1_ + t] = b * S_ + vi;
        const int g = edits[b * T_ + t + 1];
        const int vd2 = vd + ((g == 3 || g == 4) ? 1 : 0);
        const int alive = (g != 4 && g != 2 && g != 0) ? 1 : 0;
        const int vi2 = vi + alive;
        int nxt = va + 1; if (nxt > L_ - 1) nxt = L_ - 1;
        const int tok = org[b * L_ + nxt];
        const bool cond = alive && (g != 3) && (va + 1 < L_) && (tok == 103 || tok == 3 || tok == 4);
        const int va2 = cond ? (va + 1) : max(vd2, va);
        vd = vd2; vi = vi2; va = va2;
    }
}

// ---------------------------------------------------------------------------
// Fused per-row kernel: ref softmax mixing + attention + feature concat.
// ---------------------------------------------------------------------------
__global__ __launch_bounds__(256) void fused_row_kernel(
    const bf16* __restrict__ oute, const bf16* __restrict__ outa,
    const bf16* __restrict__ enc, const bf16* __restrict__ outw,
    const bf16* __restrict__ qb,
    const float* __restrict__ Wref, const float* __restrict__ bref,
    const int* __restrict__ cd, const int* __restrict__ ca,
    const int* __restrict__ cwrow,
    bf16* __restrict__ fe, bf16* __restrict__ fa)
{
    const int r = blockIdx.x;
    const int b = r / TM1_;
    const int t = r % TM1_;
    const int tid = threadIdx.x;
    const bf16* de = oute + ((size_t)b * T_ + t) * H_;
    const bf16* da = outa + ((size_t)b * T_ + t) * H_;

    __shared__ float red4[256][4];
    __shared__ float qs[H_];
    __shared__ float p[L_ + 1];
    __shared__ float red[256];

    {
        float s0 = 0.f, s1 = 0.f, s2 = 0.f, s3 = 0.f;
        for (int k = tid; k < H_; k += 256) {
            const float w0 = Wref[k];
            const float w1 = Wref[H_ + k];
            const float e = bf2f(de[k]);
            const float a = bf2f(da[k]);
            s0 += e * w0; s1 += e * w1; s2 += a * w0; s3 += a * w1;
        }
        red4[tid][0] = s0; red4[tid][1] = s1; red4[tid][2] = s2; red4[tid][3] = s3;
    }
    {
        const bf16* qrow = qb + (size_t)r * H_;
        for (int h = tid; h < H_; h += 256) qs[h] = bf2f(qrow[h]);
    }
    __syncthreads();
    for (int off = 128; off > 0; off >>= 1) {
        if (tid < off) {
            red4[tid][0] += red4[tid + off][0];
            red4[tid][1] += red4[tid + off][1];
            red4[tid][2] += red4[tid + off][2];
            red4[tid][3] += red4[tid + off][3];
        }
        __syncthreads();
    }
    const float br0 = bref[0], br1 = bref[1];
    const float xe0 = red4[0][0] + br0, xe1 = red4[0][1] + br1;
    const float xa0 = red4[0][2] + br0, xa1 = red4[0][3] + br1;
    const float me = fmaxf(xe0, xe1);
    const float ee0 = expf(xe0 - me), ee1 = expf(xe1 - me);
    const float pe0 = ee0 / (ee0 + ee1), pe1 = ee1 / (ee0 + ee1);
    const float ma = fmaxf(xa0, xa1);
    const float ea0 = expf(xa0 - ma), ea1 = expf(xa1 - ma);
    const float pa0 = ea0 / (ea0 + ea1), pa1 = ea1 / (ea0 + ea1);

    const bf16* eb = enc + (size_t)b * L_ * H_;
    float myv = -1e30f;
    if (tid < L_) {
        const unsigned* er = (const unsigned*)(eb + (size_t)tid * H_);
        float s = 0.f;
        for (int k2 = 0; k2 < H_ / 2; ++k2) {
            const unsigned u = er[k2];
            s += qs[2 * k2] * uslo(u) + qs[2 * k2 + 1] * ushi(u);
        }
        p[tid] = s;
        myv = s;
    }
    red[tid] = myv;
    __syncthreads();
    for (int off = 128; off > 0; off >>= 1) {
        if (tid < off) red[tid] = fmaxf(red[tid], red[tid + off]);
        __syncthreads();
    }
    const float m = red[0];
    __syncthreads();
    float e = 0.f;
    if (tid < L_) e = expf(p[tid] - m);
    red[tid] = e;
    __syncthreads();
    for (int off = 128; off > 0; off >>= 1) {
        if (tid < off) red[tid] += red[tid + off];
        __syncthreads();
    }
    const float invZ = 1.f / red[0];
    __syncthreads();
    if (tid < L_) p[tid] = e * invZ;
    __syncthreads();

    const bf16* ecd = enc + ((size_t)b * L_ + cd[r]) * H_;
    const bf16* eca = enc + ((size_t)b * L_ + ca[r]) * H_;
    const bf16* cwp = outw + (size_t)cwrow[r] * H_;
    bf16* pfe = fe + (size_t)r * K5_;
    bf16* pfa = fa + (size_t)r * K5_;
    for (int h = tid; h < H_; h += 256) {
        float appv = 0.f;
        for (int l = 0; l < L_; ++l) appv += p[l] * bf2f(eb[(size_t)l * H_ + h]);
        const bf16 appb = f2bf(appv);
        const float vi = bf2f(ecd[h]);
        const float va = bf2f(eca[h]);
        const bf16 cedv = f2bf(pe0 * vi + pe1 * va);
        const bf16 cacv = f2bf(pa0 * vi + pa1 * va);
        const bf16 dev = de[h], dav = da[h], cwv = cwp[h];
        pfe[h] = dev;  pfe[H_ + h] = dav;  pfe[2 * H_ + h] = appb;
        pfe[3 * H_ + h] = cedv;  pfe[4 * H_ + h] = cwv;
        pfa[h] = dav;  pfa[H_ + h] = dev;  pfa[2 * H_ + h] = appb;
        pfa[3 * H_ + h] = cacv;  pfa[4 * H_ + h] = cwv;
    }
}

// In-place log-softmax over f32 rows (edit head, N=30522).
__global__ __launch_bounds__(1024) void logsoftmax_edit_kernel(float* __restrict__ out)
{
    float* row = out + (size_t)blockIdx.x * V_;
    const int tid = threadIdx.x;
    const int lane = tid & 63;
    const int wid = tid >> 6;
    __shared__ unsigned short rowb[V_];
    __shared__ float wredm[16], wreds[16];
    __shared__ float fin;

    float m = -1e30f, s = 0.f;
    for (int i = tid; i < V_; i += 1024) {
        const float x = row[i];
        rowb[i] = f2us(x);
        if (x > m) { s = s * expf(m - x) + 1.f; m = x; }
        else s += expf(x - m);
    }
#pragma unroll
    for (int off = 32; off > 0; off >>= 1) {
        const float m2 = __shfl_down(m, off);
        const float s2 = __shfl_down(s, off);
        const float mn = fmaxf(m, m2);
        s = s * expf(m - mn) + s2 * expf(m2 - mn);
        m = mn;
    }
    if (lane == 0) { wredm[wid] = m; wreds[wid] = s; }
    __syncthreads();
    if (wid == 0) {
        m = (lane < 16) ? wredm[lane] : -1e30f;
        s = (lane < 16) ? wreds[lane] : 0.f;
#pragma unroll
        for (int off = 8; off > 0; off >>= 1) {
            const float m2 = __shfl_down(m, off);
            const float s2 = __shfl_down(s, off);
            const float mn = fmaxf(m, m2);
            s = s * expf(m - mn) + s2 * expf(m2 - mn);
            m = mn;
        }
        if (lane == 0) fin = m + logf(s);
    }
    __syncthreads();
    const float lz = fin;
    for (int i = tid; i < V_; i += 1024) row[i] = us2f(rowb[i]) - lz;
}

// Act head log-softmax: f32 in -> f32 out
__global__ __launch_bounds__(256) void logsoftmax_act_kernel(const float* __restrict__ in,
                                                             float* __restrict__ out)
{
    const float* row = in + (size_t)blockIdx.x * AV_;
    float* orow = out + (size_t)blockIdx.x * AV_;
    const int tid = threadIdx.x;
    __shared__ float red[256];
    float m = -1e30f;
    if (tid < AV_) m = row[tid];
    red[tid] = m;
    __syncthreads();
    for (int off = 128; off > 0; off >>= 1) {
        if (tid < off) red[tid] = fmaxf(red[tid], red[tid + off]);
        __syncthreads();
    }
    m = red[0];
    __syncthreads();
    float s = 0.f;
    if (tid < AV_) s = expf(row[tid] - m);
    red[tid] = s;
    __syncthreads();
    for (int off = 128; off > 0; off >>= 1) {
        if (tid < off) red[tid] += red[tid + off];
        __syncthreads();
    }
    const float lz = m + logf(red[0]);
    if (tid < AV_) orow[tid] = row[tid] - lz;
}

// ---------------------------------------------------------------------------
extern "C" void kernel_launch(void* const* d_in, const int* in_sizes, int n_in,
                              void* d_out, int out_size, void* d_ws, size_t ws_size,
                              hipStream_t stream)
{
    const int* input_edits   = (const int*)d_in[0];
    const int* input_actions = (const int*)d_in[1];
    const int* simp_sent     = (const int*)d_in[2];
    const int* org_ids       = (const int*)d_in[3];
    const float* enc_org     = (const float*)d_in[4];
    const float* emb         = (const float*)d_in[5];
    const float* Wih_e = (const float*)d_in[6];
    const float* Whh_e = (const float*)d_in[7];
    const float* bih_e = (const float*)d_in[8];
    const float* bhh_e = (const float*)d_in[9];
    const float* Wih_a = (const float*)d_in[10];
    const float* Whh_a = (const float*)d_in[11];
    const float* bih_a = (const float*)d_in[12];
    const float* bhh_a = (const float*)d_in[13];
    const float* Wih_w = (const float*)d_in[14];
    const float* Whh_w = (const float*)d_in[15];
    const float* bih_w = (const float*)d_in[16];
    const float* bhh_w = (const float*)d_in[17];
    const float* W_align = (const float*)d_in[18];
    const float* W_proj  = (const float*)d_in[19];
    const float* W_ref   = (const float*)d_in[20];
    const float* b_ref   = (const float*)d_in[21];
    const float* W_mlp   = (const float*)d_in[22];
    const float* b_mlp   = (const float*)d_in[23];
    const float* W_act   = (const float*)d_in[24];
    const float* b_act   = (const float*)d_in[25];
    const float* W_out   = (const float*)d_in[26];
    const float* b_out   = (const float*)d_in[27];
    const float* W_outact = (const float*)d_in[28];
    const float* b_outact = (const float*)d_in[29];
    const float* action_mask = (const float*)d_in[30];

    float* out = (float*)d_out;
    float* edit_out = out;                               // (2032, 30522) f32
    float* act_out  = out + (size_t)R_ * V_;             // (2032, 200)   f32

    // Workspace layout
    char* p = (char*)d_ws;
    auto take = [&](size_t bytes) { void* q = (void*)p; p += ((bytes + 255) / 256) * 256; return q; };
    int* flags = (int*)take(3 * 256);
    unsigned short* hbuf = (unsigned short*)take((size_t)3 * 2 * B_ * H_ * 2);
    char* alias_base = p;                                // xe..pxw region (dead after LSTM)
    bf16* xe   = (bf16*)take((size_t)B_ * T_ * H_ * 2);
    bf16* xa   = (bf16*)take((size_t)B_ * T_ * H_ * 2);
    bf16* xw   = (bf16*)take((size_t)B_ * S_ * H_ * 2);
    bf16* pxe  = (bf16*)take((size_t)B_ * T_ * G4_ * 2);
    bf16* pxa  = (bf16*)take((size_t)B_ * T_ * G4_ * 2);
    bf16* pxw  = (bf16*)take((size_t)B_ * S_ * G4_ * 2);
    bf16* oute = (bf16*)take((size_t)B_ * T_ * H_ * 2);
    bf16* outa = (bf16*)take((size_t)B_ * T_ * H_ * 2);
    bf16* outw = (bf16*)take((size_t)B_ * S_ * H_ * 2);
    bf16* enc  = (bf16*)take((size_t)B_ * L_ * H_ * 2);
    bf16* qb   = (bf16*)take((size_t)R_ * H_ * 2);
    bf16* fe   = (bf16*)take((size_t)R_ * K5_ * 2);
    bf16* fa   = (bf16*)take((size_t)R_ * K5_ * 2);
    bf16* he   = (bf16*)take((size_t)R_ * H_ * 2);
    bf16* ha   = (bf16*)take((size_t)R_ * H_ * 2);
    int*  cd   = (int*)take((size_t)R_ * 4);
    int*  ci   = (int*)take((size_t)R_ * 4);
    int*  ca   = (int*)take((size_t)R_ * 4);
    int*  cwrow = (int*)take((size_t)R_ * 4);
    float* actbuf = (float*)take((size_t)R_ * AV_ * 4);
    bf16* Wmlpb = (bf16*)take((size_t)H_ * K5_ * 2);
    bf16* Wactb = (bf16*)take((size_t)H_ * K5_ * 2);
    bf16* Woab  = (bf16*)take((size_t)AV_ * H_ * 2);
    // W_out bf16 aliases xe..pxw (55 MB >= 46.9 MB), converted during LSTM.
    bf16* Wob = (bf16*)alias_base;
    // Wih bf16 copies alias fe (dead until fused_row writes feats).
    bf16* WihEb = fe;
    bf16* WihAb = fe + (size_t)G4_ * H_;
    bf16* WihWb = fe + (size_t)2 * G4_ * H_;
    // enc_org/W_align/W_proj bf16 copies alias fa (dead until fused_row).
    bf16* encb   = fa;
    bf16* Walb   = fa + (size_t)B_ * S_ * H_;
    bf16* Wprojb = fa + (size_t)B_ * S_ * H_ + (size_t)H_ * H_;

    // 0. Zero barrier flags
    hipMemsetAsync(flags, 0, 3 * 256, stream);

    // 0.5 Convert all f32 GEMM operands to bf16 (one pass, 9 matrices)
    ConvJobs jobs;
    jobs.src[0] = Wih_e;   jobs.dst[0] = WihEb;  jobs.n4[0] = G4_ * H_ / 4;
    jobs.src[1] = Wih_a;   jobs.dst[1] = WihAb;  jobs.n4[1] = G4_ * H_ / 4;
    jobs.src[2] = Wih_w;   jobs.dst[2] = WihWb;  jobs.n4[2] = G4_ * H_ / 4;
    jobs.src[3] = W_mlp;   jobs.dst[3] = Wmlpb;  jobs.n4[3] = H_ * K5_ / 4;
    jobs.src[4] = W_act;   jobs.dst[4] = Wactb;  jobs.n4[4] = H_ * K5_ / 4;
    jobs.src[5] = enc_org; jobs.dst[5] = encb;   jobs.n4[5] = B_ * S_ * H_ / 4;
    jobs.src[6] = W_align; jobs.dst[6] = Walb;   jobs.n4[6] = H_ * H_ / 4;
    jobs.src[7] = W_proj;  jobs.dst[7] = Wprojb; jobs.n4[7] = H_ * H_ / 4;
    jobs.src[8] = W_outact;jobs.dst[8] = Woab;   jobs.n4[8] = AV_ * H_ / 4;
    conv_many_kernel<<<dim3((H_ * K5_ / 4 + 255) / 256, 9), 256, 0, stream>>>(jobs);

    // 1. Embedding gathers (fused)
    gather3_kernel<<<dim3(B_ * S_, 3), 256, 0, stream>>>(
        input_edits, input_actions, simp_sent, emb, xe, xa, xw);

    // 2. px = x@Wih^T + bih + bhh (256-row M-tiles: W panel staged once per 256 rows)
    dim3 gpx2((B_ * T_ + 255) / 256, (G4_ + 127) / 128);
    gemm_mfma2<<<gpx2, 256, 0, stream>>>(xe, WihEb, bih_e, bhh_e, pxe, nullptr, B_ * T_, G4_, H_, 0, H_);
    gemm_mfma2<<<gpx2, 256, 0, stream>>>(xa, WihAb, bih_a, bhh_a, pxa, nullptr, B_ * T_, G4_, H_, 0, H_);
    dim3 gpxw2((B_ * S_ + 255) / 256, (G4_ + 127) / 128);
    gemm_mfma2<<<gpxw2, 256, 0, stream>>>(xw, WihWb, bih_w, bhh_w, pxw, nullptr, B_ * S_, G4_, H_, 0, H_);

    // 3. enc = tanh(enc_org @ W_align^T)[:, 1:]  (rowdiv path, 128-row tiles)
    dim3 genc((B_ * L_ + 127) / 128, (H_ + 127) / 128);
    gemm_mfma<<<genc, 256, 0, stream>>>(encb, Walb, nullptr, nullptr, enc, nullptr, B_ * L_, H_, H_, 1, L_, H_, nullptr);

    // 4. Counters scan (+ cwrow)
    counters_kernel<<<1, 64, 0, stream>>>(input_edits, org_ids, cd, ci, ca, cwrow);

    // 5. Persistent cooperative LSTMs + folded W_out->bf16 converter blocks
    lstm_mfma_kernel<<<3 * NB_ + NCV_, 256, 0, stream>>>(pxe, pxa, pxw, Whh_e, Whh_a, Whh_w,
                                                         oute, outa, outw, hbuf, flags,
                                                         W_out, Wob);

    // 6. q = c_word @ W_proj^T (row-gather GEMM)
    dim3 gproj((R_ + 127) / 128, (H_ + 127) / 128);
    gemm_mfma<<<gproj, 256, 0, stream>>>(outw, Wprojb, nullptr, nullptr, qb, nullptr, R_, H_, H_, 0, 0, H_, cwrow);

    // 7. fused ref-mix + attention + feature concat
    fused_row_kernel<<<R_, 256, 0, stream>>>(oute, outa, enc, outw, qb,
                                             W_ref, b_ref, cd, ca, cwrow, fe, fa);

    // 8. hidden layers (tanh, K=3840, 256-row M-tiles)
    dim3 gh2((R_ + 255) / 256, (H_ + 127) / 128);
    gemm_mfma2<<<gh2, 256, 0, stream>>>(fe, Wmlpb, b_mlp, nullptr, he, nullptr, R_, H_, K5_, 1, K5_);
    gemm_mfma2<<<gh2, 256, 0, stream>>>(fa, Wactb, b_act, nullptr, ha, nullptr, R_, H_, K5_, 1, K5_);

    // 9. act head + log-softmax
    dim3 gact((R_ + 127) / 128, (AV_ + 127) / 128);
    gemm_mfma<<<gact, 256, 0, stream>>>(ha, Woab, b_outact, action_mask, nullptr, actbuf, R_, AV_, H_, 0, 0, H_, nullptr);
    logsoftmax_act_kernel<<<R_, 256, 0, stream>>>(actbuf, act_out);

    // 10. edit head (bf16 W, 256-row M-tiles) + in-place log-softmax
    dim3 gedit2((R_ + 255) / 256, (V_ + 127) / 128);
    gemm_mfma2<<<gedit2, 256, 0, stream>>>(he, Wob, b_out, nullptr, nullptr, edit_out, R_, V_, H_, 0, H_);
    logsoftmax_edit_kernel<<<R_, 1024, 0, stream>>>(edit_out);
}

// Round 17
// 2129.605 us; speedup vs baseline: 1.1653x; 1.1653x over previous
//
#include <hip/hip_runtime.h>
#include <hip/hip_bf16.h>

typedef __hip_bfloat16 bf16;

// Problem dims
#define B_    16
#define T_    128
#define S_    192
#define H_    768
#define G4_   3072      // 4*H
#define V_    30522
#define AV_   200
#define L_    191       // L_SRC-1
#define TM1_  127       // T-1
#define R_    2032      // B*(T-1)
#define K5_   3840      // 5*H
#define NB_   48        // blocks per LSTM (persistent)
#define HSL_  16        // h-slice per block (768/48)
#define NCV_  96        // converter blocks appended to the LSTM grid

typedef short bf16x8_t __attribute__((ext_vector_type(8)));
typedef float f32x4_t  __attribute__((ext_vector_type(4)));

__device__ __forceinline__ float bf2f(bf16 v) { return __bfloat162float(v); }
__device__ __forceinline__ bf16  f2bf(float v) { return __float2bfloat16(v); }
__device__ __forceinline__ unsigned short f2us(float v) { bf16 h = f2bf(v); return *reinterpret_cast<unsigned short*>(&h); }
__device__ __forceinline__ float uslo(unsigned u) { union { unsigned i; float f; } x; x.i = u << 16; return x.f; }
__device__ __forceinline__ float ushi(unsigned u) { union { unsigned i; float f; } x; x.i = u & 0xffff0000u; return x.f; }
__device__ __forceinline__ float us2f(unsigned short u) { union { unsigned i; float f; } x; x.i = ((unsigned)u) << 16; return x.f; }
__device__ __forceinline__ float sigm(float x) { return 1.0f / (1.0f + expf(-x)); }

// 8-element bf16 fragment loads (optionally converting from f32)
__device__ __forceinline__ bf16x8_t ld8bf(const bf16* p) { return *(const bf16x8_t*)p; }
__device__ __forceinline__ bf16x8_t ld8bf(const float* p) {
    float4 a = *(const float4*)p;
    float4 b = *(const float4*)(p + 4);
    bf16x8_t r;
    r[0] = (short)f2us(a.x); r[1] = (short)f2us(a.y); r[2] = (short)f2us(a.z); r[3] = (short)f2us(a.w);
    r[4] = (short)f2us(b.x); r[5] = (short)f2us(b.y); r[6] = (short)f2us(b.z); r[7] = (short)f2us(b.w);
    return r;
}

// async global->LDS, 16B per lane; LDS dest = uniform base + lane*16
#define GLDS(gptr, lptr) \
    __builtin_amdgcn_global_load_lds((const __attribute__((address_space(1))) void*)(gptr), \
                                     (__attribute__((address_space(3))) void*)(lptr), 16, 0, 0)

// ---------------------------------------------------------------------------
// MFMA GEMM (bf16 x bf16): C[M,N] = act( A[M,K] * W[N,K]^T + bias1 + bias2 )
// 128x128 tile, 256 threads (4 waves 2x2), K-step 64.
// Staging via global_load_lds width 16 into UNPADDED [128][64] LDS tiles with
// XOR chunk swizzle: LDS(row, c) holds global (row, c^(row&7)); the per-lane
// GLOBAL source is pre-swizzled (linear LDS dest), reads apply c = gc^(r&7).
// ds_read bank aliasing: 2 lanes/bank (free). rowdiv>0 remaps A rows
// r -> r + r/rowdiv + 1 (the enc [:,1:] slice). K % 64 == 0.
// ---------------------------------------------------------------------------
__global__ __launch_bounds__(256) void gemm_mfma(
    const bf16* __restrict__ A, const bf16* __restrict__ W,
    const float* __restrict__ bias1, const float* __restrict__ bias2,
    bf16* __restrict__ Ch, float* __restrict__ Cf,
    int M, int N, int K, int act, int rowdiv, int lda)
{
    __shared__ short As[128 * 64];   // 16 KB, unpadded
    __shared__ short Ws[128 * 64];
    const int tid = threadIdx.x;
    const int wave = tid >> 6, lane = tid & 63;
    const int mw = (wave >> 1) * 64, nw = (wave & 1) * 64;
    const int bm = blockIdx.x * 128, bn = blockIdx.y * 128;

    // per-lane swizzled source chunk: row&7 == lane>>3 for every issue
    const int schunk = (lane & 7) ^ (lane >> 3);

    // per-issue global row bases (fixed across K)
    const bf16* aSrc[4];
    const bf16* wSrc[4];
#pragma unroll
    for (int j = 0; j < 4; ++j) {
        const int idx = wave * 4 + j;          // LDS chunk-of-8-rows index
        const int srow = idx * 8 + (lane >> 3);
        int ga = bm + srow; if (ga > M - 1) ga = M - 1;
        const int ra = (rowdiv > 0) ? (ga + ga / rowdiv + 1) : ga;
        aSrc[j] = A + (size_t)ra * lda + schunk * 8;
        int gw = bn + srow; if (gw > N - 1) gw = N - 1;
        wSrc[j] = W + (size_t)gw * K + schunk * 8;
    }

    f32x4_t acc[4][4];
#pragma unroll
    for (int mi = 0; mi < 4; ++mi)
#pragma unroll
        for (int ni = 0; ni < 4; ++ni) acc[mi][ni] = (f32x4_t){0.f, 0.f, 0.f, 0.f};

    const int fr = lane & 15;
    const int fr7 = fr & 7;
    const int cq = lane >> 4;      // 0..3

    for (int k0 = 0; k0 < K; k0 += 64) {
#pragma unroll
        for (int j = 0; j < 4; ++j) {
            const int idx = wave * 4 + j;
            GLDS(aSrc[j] + k0, &As[idx * 512]);
            GLDS(wSrc[j] + k0, &Ws[idx * 512]);
        }
        __syncthreads();
#pragma unroll
        for (int half = 0; half < 2; ++half) {
            const int gc = half * 4 + cq;              // global k-chunk wanted
            const int lc = (gc ^ fr7) * 8;             // swizzled LDS chunk (shorts)
            bf16x8_t af[4], wf[4];
#pragma unroll
            for (int i = 0; i < 4; ++i)
                af[i] = *(const bf16x8_t*)&As[(mw + i * 16 + fr) * 64 + lc];
#pragma unroll
            for (int i = 0; i < 4; ++i)
                wf[i] = *(const bf16x8_t*)&Ws[(nw + i * 16 + fr) * 64 + lc];
#pragma unroll
            for (int mi = 0; mi < 4; ++mi)
#pragma unroll
                for (int ni = 0; ni < 4; ++ni)
                    acc[mi][ni] = __builtin_amdgcn_mfma_f32_16x16x32_bf16(af[mi], wf[ni], acc[mi][ni], 0, 0, 0);
        }
        __syncthreads();
    }

    const int cl = lane & 15;
    const int rg = (lane >> 4) * 4;
#pragma unroll
    for (int mi = 0; mi < 4; ++mi) {
#pragma unroll
        for (int ni = 0; ni < 4; ++ni) {
            const int col = bn + nw + ni * 16 + cl;
            if (col >= N) continue;
#pragma unroll
            for (int j = 0; j < 4; ++j) {
                const int row = bm + mw + mi * 16 + rg + j;
                if (row >= M) continue;
                float v = acc[mi][ni][j];
                if (bias1) v += bias1[col];
                if (bias2) v += bias2[col];
                if (act == 1) v = tanhf(v);
                if (Ch) Ch[(size_t)row * N + col] = f2bf(v);
                else    Cf[(size_t)row * N + col] = v;
            }
        }
    }
}

// ---------------------------------------------------------------------------
// Batch f32 -> bf16 conversion of 9 matrices
// ---------------------------------------------------------------------------
struct ConvJobs {
    const float* src[9];
    bf16* dst[9];
    int n4[9];
};
__global__ void conv_many_kernel(ConvJobs jobs)
{
    const int w = blockIdx.y;
    const int i = blockIdx.x * 256 + threadIdx.x;
    if (i >= jobs.n4[w]) return;
    const float* s = jobs.src[w];
    bf16* d = jobs.dst[w];
    float4 v = *(const float4*)(s + (size_t)i * 4);
    ushort4 o;
    o.x = f2us(v.x); o.y = f2us(v.y); o.z = f2us(v.z); o.w = f2us(v.w);
    *(ushort4*)(d + (size_t)i * 4) = o;
}

// ---------------------------------------------------------------------------
// Persistent cooperative LSTM + W_out converter worker blocks (round-12 logic).
// ---------------------------------------------------------------------------
__global__ __launch_bounds__(256) void lstm_mfma_kernel(
    const bf16* __restrict__ pxe, const bf16* __restrict__ pxa, const bf16* __restrict__ pxw,
    const float* __restrict__ We, const float* __restrict__ Wa, const float* __restrict__ Ww,
    bf16* __restrict__ oute, bf16* __restrict__ outa, bf16* __restrict__ outw,
    unsigned short* __restrict__ hbuf, int* __restrict__ flags,
    const float* __restrict__ Wout, bf16* __restrict__ Wob)
{
    const int tid = threadIdx.x;

    if (blockIdx.x >= 3 * NB_) {
        const int wid = blockIdx.x - 3 * NB_;
        const int n4 = V_ * H_ / 4;
        for (int i = wid * 256 + tid; i < n4; i += NCV_ * 256) {
            float4 v = *(const float4*)(Wout + (size_t)i * 4);
            ushort4 o;
            o.x = f2us(v.x); o.y = f2us(v.y); o.z = f2us(v.z); o.w = f2us(v.w);
            *(ushort4*)(Wob + (size_t)i * 4) = o;
        }
        return;
    }

    const int which = blockIdx.x / NB_;
    const int nb = blockIdx.x % NB_;
    const bf16* px; const float* W; bf16* out; int Tn;
    if (which == 0)      { px = pxe; W = We; out = oute; Tn = T_; }
    else if (which == 1) { px = pxa; W = Wa; out = outa; Tn = T_; }
    else                 { px = pxw; W = Ww; out = outw; Tn = S_; }
    unsigned short* hG = hbuf + (size_t)which * (2 * B_ * H_);
    int* flg = flags + which * 64;

    const int wv = tid >> 6;
    const int lane = tid & 63;
    const int so = nb * HSL_;

    __shared__ unsigned short hL[16][776];
    __shared__ float gS[4][16][17];
    __shared__ unsigned short oring[8][16][16];

    bf16x8_t Afrag[24];
    {
        const int m = lane & 15;
        const int kb8 = (lane >> 4) * 8;
        const float* wrow = W + (size_t)(wv * H_ + so + m) * H_ + kb8;
#pragma unroll
        for (int kb = 0; kb < 24; ++kb) {
            float4 f0 = *(const float4*)(wrow + kb * 32);
            float4 f1 = *(const float4*)(wrow + kb * 32 + 4);
            bf16x8_t a;
            a[0] = (short)f2us(f0.x); a[1] = (short)f2us(f0.y);
            a[2] = (short)f2us(f0.z); a[3] = (short)f2us(f0.w);
            a[4] = (short)f2us(f1.x); a[5] = (short)f2us(f1.y);
            a[6] = (short)f2us(f1.z); a[7] = (short)f2us(f1.w);
            Afrag[kb] = a;
        }
    }

    for (int i = tid; i < 16 * 776; i += 256) ((unsigned short*)hL)[i] = 0;

    const int cb = tid >> 4;
    const int chl = tid & 15;
    float c = 0.f;

    const int bn = lane & 15;
    const int bk = (lane >> 4) * 8;

    unsigned short pxr0, pxr1, pxr2, pxr3;
    {
        const bf16* q = px + ((size_t)cb * Tn + 0) * G4_ + so + chl;
        pxr0 = *(const unsigned short*)(q);
        pxr1 = *(const unsigned short*)(q + H_);
        pxr2 = *(const unsigned short*)(q + 2 * H_);
        pxr3 = *(const unsigned short*)(q + 3 * H_);
    }

    int cur = 0;
    for (int step = 0; step < Tn; ++step) {
        if (step > 0) {
            const unsigned long long* hsrc =
                (const unsigned long long*)(hG + (size_t)cur * (B_ * H_));
            for (int i = tid; i < B_ * H_ / 4; i += 256) {
                const unsigned long long v =
                    __hip_atomic_load(hsrc + i, __ATOMIC_RELAXED, __HIP_MEMORY_SCOPE_AGENT);
                const int bb = i / (H_ / 4);
                const int cc = i - bb * (H_ / 4);
                ((unsigned long long*)&hL[bb][0])[cc] = v;
            }
        }
        __syncthreads();

        f32x4_t acc = {0.f, 0.f, 0.f, 0.f};
#pragma unroll
        for (int kb = 0; kb < 24; ++kb) {
            bf16x8_t bfr = *(const bf16x8_t*)&hL[bn][kb * 32 + bk];
            acc = __builtin_amdgcn_mfma_f32_16x16x32_bf16(Afrag[kb], bfr, acc, 0, 0, 0);
        }
        {
            const int m0 = (lane >> 4) * 4;
#pragma unroll
            for (int j = 0; j < 4; ++j) gS[wv][m0 + j][bn] = acc[j];
        }
        __syncthreads();

        {
            const float gi = gS[0][chl][cb] + us2f(pxr0);
            const float gf = gS[1][chl][cb] + us2f(pxr1);
            const float gg = gS[2][chl][cb] + us2f(pxr2);
            const float go = gS[3][chl][cb] + us2f(pxr3);
            const float cn = sigm(gf) * c + sigm(gi) * tanhf(gg);
            const float hn = sigm(go) * tanhf(cn);
            c = cn;
            oring[step & 7][cb][chl] = f2us(hn);
            __hip_atomic_store(&hG[(size_t)(cur ^ 1) * (B_ * H_) + cb * H_ + so + chl],
                               f2us(hn), __ATOMIC_RELAXED, __HIP_MEMORY_SCOPE_AGENT);
        }

        if (step + 1 < Tn) {
            __syncthreads();
            const int target = step + 1;
            if (tid == 0)
                __hip_atomic_store(&flg[nb], target, __ATOMIC_RELAXED, __HIP_MEMORY_SCOPE_AGENT);
            {
                const bf16* q = px + ((size_t)cb * Tn + target) * G4_ + so + chl;
                pxr0 = *(const unsigned short*)(q);
                pxr1 = *(const unsigned short*)(q + H_);
                pxr2 = *(const unsigned short*)(q + 2 * H_);
                pxr3 = *(const unsigned short*)(q + 3 * H_);
            }
            if ((step & 7) == 7) {
                const int base = step & ~7;
                for (int s2 = 0; s2 < 8; ++s2)
                    out[((size_t)cb * Tn + base + s2) * H_ + so + chl] =
                        *reinterpret_cast<const bf16*>(&oring[s2][cb][chl]);
            }
            if (lane < NB_) {
                long guard = 0;
                while (__hip_atomic_load(&flg[lane], __ATOMIC_RELAXED, __HIP_MEMORY_SCOPE_AGENT) < target) {
                    __builtin_amdgcn_s_sleep(1);
                    if (++guard > 50000000L) break;
                }
            }
        } else {
            const int base = step & ~7;
            const int cnt8 = (step & 7) + 1;
            for (int s2 = 0; s2 < cnt8; ++s2)
                out[((size_t)cb * Tn + base + s2) * H_ + so + chl] =
                    *reinterpret_cast<const bf16*>(&oring[s2][cb][chl]);
        }
        cur ^= 1;
    }
}

// ---------------------------------------------------------------------------
// Fused row gathers: out[r][:] = bf16(emb[ids[r]][:]) for 3 id arrays
// ---------------------------------------------------------------------------
__global__ void gather3_kernel(const int* __restrict__ ids_e, const int* __restrict__ ids_a,
                               const int* __restrict__ ids_w, const float* __restrict__ emb,
                               bf16* __restrict__ oe, bf16* __restrict__ oa,
                               bf16* __restrict__ ow)
{
    const int which = blockIdx.y;
    const int r = blockIdx.x;
    const int* ids; bf16* out; int nr;
    if (which == 0)      { ids = ids_e; out = oe; nr = B_ * T_; }
    else if (which == 1) { ids = ids_a; out = oa; nr = B_ * T_; }
    else                 { ids = ids_w; out = ow; nr = B_ * S_; }
    if (r >= nr) return;
    const float4* src = (const float4*)(emb + (size_t)ids[r] * H_);
    ushort4* dst = (ushort4*)(out + (size_t)r * H_);
    for (int h = threadIdx.x; h < H_ / 4; h += 256) {
        float4 v = src[h];
        ushort4 o;
        o.x = f2us(v.x); o.y = f2us(v.y); o.z = f2us(v.z); o.w = f2us(v.w);
        dst[h] = o;
    }
}

// ---------------------------------------------------------------------------
// Counters scan
// ---------------------------------------------------------------------------
__global__ void counters_kernel(const int* __restrict__ edits, const int* __restrict__ org,
                                int* __restrict__ cd, int* __restrict__ ci, int* __restrict__ ca)
{
    const int b = threadIdx.x;
    if (b >= B_) return;
    int vd = 0, vi = 0, va = 0;
    for (int t = 0; t < TM1_; ++t) {
        cd[b * TM1_ + t] = vd; ci[b * TM1_ + t] = vi; ca[b * TM1_ + t] = va;
        const int g = edits[b * T_ + t + 1];
        const int vd2 = vd + ((g == 3 || g == 4) ? 1 : 0);
        const int alive = (g != 4 && g != 2 && g != 0) ? 1 : 0;
        const int vi2 = vi + alive;
        int nxt = va + 1; if (nxt > L_ - 1) nxt = L_ - 1;
        const int tok = org[b * L_ + nxt];
        const bool cond = alive && (g != 3) && (va + 1 < L_) && (tok == 103 || tok == 3 || tok == 4);
        const int va2 = cond ? (va + 1) : max(vd2, va);
        vd = vd2; vi = vi2; va = va2;
    }
}

// c_word[r][:] = out_w[b][ci[r]][:]
__global__ void gather_cword_kernel(const bf16* __restrict__ outw, const int* __restrict__ ci,
                                    bf16* __restrict__ cw)
{
    const int r = blockIdx.x;
    const int b = r / TM1_;
    const unsigned* src = (const unsigned*)(outw + ((size_t)b * S_ + ci[r]) * H_);
    unsigned* dst = (unsigned*)(cw + (size_t)r * H_);
    for (int h = threadIdx.x; h < H_ / 2; h += 256) dst[h] = src[h];
}

// ---------------------------------------------------------------------------
// wref softmax (2-way) + mix c_input/c_anno
// ---------------------------------------------------------------------------
__global__ __launch_bounds__(256) void ref_combine_kernel(
    const bf16* __restrict__ oute, const bf16* __restrict__ outa, const bf16* __restrict__ enc,
    const float* __restrict__ Wref, const float* __restrict__ bref,
    const int* __restrict__ cd, const int* __restrict__ ca,
    bf16* __restrict__ ced, bf16* __restrict__ cac)
{
    const int r = blockIdx.x;
    const int b = r / TM1_;
    const int t = r % TM1_;
    const bf16* de = oute + ((size_t)b * T_ + t) * H_;
    const bf16* da = outa + ((size_t)b * T_ + t) * H_;
    const int tid = threadIdx.x;
    __shared__ float red[256][4];
    float s0 = 0.f, s1 = 0.f, s2 = 0.f, s3 = 0.f;
    for (int k = tid; k < H_; k += 256) {
        const float w0 = Wref[k];
        const float w1 = Wref[H_ + k];
        const float e = bf2f(de[k]);
        const float a = bf2f(da[k]);
        s0 += e * w0; s1 += e * w1; s2 += a * w0; s3 += a * w1;
    }
    red[tid][0] = s0; red[tid][1] = s1; red[tid][2] = s2; red[tid][3] = s3;
    __syncthreads();
    for (int off = 128; off > 0; off >>= 1) {
        if (tid < off) {
            red[tid][0] += red[tid + off][0];
            red[tid][1] += red[tid + off][1];
            red[tid][2] += red[tid + off][2];
            red[tid][3] += red[tid + off][3];
        }
        __syncthreads();
    }
    const float br0 = bref[0], br1 = bref[1];
    const float xe0 = red[0][0] + br0, xe1 = red[0][1] + br1;
    const float xa0 = red[0][2] + br0, xa1 = red[0][3] + br1;
    const float me = fmaxf(xe0, xe1);
    const float ee0 = expf(xe0 - me), ee1 = expf(xe1 - me);
    const float pe0 = ee0 / (ee0 + ee1), pe1 = ee1 / (ee0 + ee1);
    const float ma = fmaxf(xa0, xa1);
    const float ea0 = expf(xa0 - ma), ea1 = expf(xa1 - ma);
    const float pa0 = ea0 / (ea0 + ea1), pa1 = ea1 / (ea0 + ea1);

    const bf16* ei = enc + ((size_t)b * L_ + cd[r]) * H_;
    const bf16* ea = enc + ((size_t)b * L_ + ca[r]) * H_;
    for (int h = tid; h < H_; h += 256) {
        const float vi = bf2f(ei[h]);
        const float va = bf2f(ea[h]);
        ced[(size_t)r * H_ + h] = f2bf(pe0 * vi + pe1 * va);
        cac[(size_t)r * H_ + h] = f2bf(pa0 * vi + pa1 * va);
    }
}

// ---------------------------------------------------------------------------
// Attention over L=191
// ---------------------------------------------------------------------------
__global__ __launch_bounds__(256) void attn_kernel(const bf16* __restrict__ q,
                                                   const bf16* __restrict__ enc,
                                                   bf16* __restrict__ app)
{
    const int r = blockIdx.x;
    const int b = r / TM1_;
    const int tid = threadIdx.x;
    __shared__ float qs[H_];
    __shared__ float p[L_ + 1];
    __shared__ float red[256];
    const bf16* qrow = q + (size_t)r * H_;
    for (int h = tid; h < H_; h += 256) qs[h] = bf2f(qrow[h]);
    __syncthreads();
    const bf16* eb = enc + (size_t)b * L_ * H_;
    float myv = -1e30f;
    if (tid < L_) {
        const unsigned* er = (const unsigned*)(eb + (size_t)tid * H_);
        float s = 0.f;
        for (int k2 = 0; k2 < H_ / 2; ++k2) {
            const unsigned u = er[k2];
            s += qs[2 * k2] * uslo(u) + qs[2 * k2 + 1] * ushi(u);
        }
        p[tid] = s;
        myv = s;
    }
    red[tid] = myv;
    __syncthreads();
    for (int off = 128; off > 0; off >>= 1) {
        if (tid < off) red[tid] = fmaxf(red[tid], red[tid + off]);
        __syncthreads();
    }
    const float m = red[0];
    __syncthreads();
    float e = 0.f;
    if (tid < L_) e = expf(p[tid] - m);
    red[tid] = e;
    __syncthreads();
    for (int off = 128; off > 0; off >>= 1) {
        if (tid < off) red[tid] += red[tid + off];
        __syncthreads();
    }
    const float invZ = 1.f / red[0];
    __syncthreads();
    if (tid < L_) p[tid] = e * invZ;
    __syncthreads();
    for (int h = tid; h < H_; h += 256) {
        float s = 0.f;
        for (int l = 0; l < L_; ++l) s += p[l] * bf2f(eb[(size_t)l * H_ + h]);
        app[(size_t)r * H_ + h] = f2bf(s);
    }
}

// feat_e = [dec_e, dec_a, app, ced, cw]; feat_a = [dec_a, dec_e, app, cac, cw]
__global__ void feat_kernel(const bf16* __restrict__ oute, const bf16* __restrict__ outa,
                            const bf16* __restrict__ app, const bf16* __restrict__ ced,
                            const bf16* __restrict__ cac, const bf16* __restrict__ cw,
                            bf16* __restrict__ fe, bf16* __restrict__ fa)
{
    const int r = blockIdx.x;
    const int b = r / TM1_;
    const int t = r % TM1_;
    const unsigned* de  = (const unsigned*)(oute + ((size_t)b * T_ + t) * H_);
    const unsigned* da  = (const unsigned*)(outa + ((size_t)b * T_ + t) * H_);
    const unsigned* ap  = (const unsigned*)(app + (size_t)r * H_);
    const unsigned* ce  = (const unsigned*)(ced + (size_t)r * H_);
    const unsigned* cA  = (const unsigned*)(cac + (size_t)r * H_);
    const unsigned* cwp = (const unsigned*)(cw + (size_t)r * H_);
    unsigned* pfe = (unsigned*)(fe + (size_t)r * K5_);
    unsigned* pfa = (unsigned*)(fa + (size_t)r * K5_);
    const int HW = H_ / 2;
    for (int h = threadIdx.x; h < HW; h += 256) {
        const unsigned ve = de[h], va = da[h], vap = ap[h], vce = ce[h], vca = cA[h], vcw = cwp[h];
        pfe[h] = ve;  pfe[HW + h] = va;  pfe[2 * HW + h] = vap; pfe[3 * HW + h] = vce; pfe[4 * HW + h] = vcw;
        pfa[h] = va;  pfa[HW + h] = ve;  pfa[2 * HW + h] = vap; pfa[3 * HW + h] = vca; pfa[4 * HW + h] = vcw;
    }
}

// In-place log-softmax over f32 rows (edit head, N=30522).
__global__ __launch_bounds__(1024) void logsoftmax_edit_kernel(float* __restrict__ out)
{
    float* row = out + (size_t)blockIdx.x * V_;
    const int tid = threadIdx.x;
    const int lane = tid & 63;
    const int wid = tid >> 6;
    __shared__ unsigned short rowb[V_];
    __shared__ float wredm[16], wreds[16];
    __shared__ float fin;

    float m = -1e30f, s = 0.f;
    for (int i = tid; i < V_; i += 1024) {
        const float x = row[i];
        rowb[i] = f2us(x);
        if (x > m) { s = s * expf(m - x) + 1.f; m = x; }
        else s += expf(x - m);
    }
#pragma unroll
    for (int off = 32; off > 0; off >>= 1) {
        const float m2 = __shfl_down(m, off);
        const float s2 = __shfl_down(s, off);
        const float mn = fmaxf(m, m2);
        s = s * expf(m - mn) + s2 * expf(m2 - mn);
        m = mn;
    }
    if (lane == 0) { wredm[wid] = m; wreds[wid] = s; }
    __syncthreads();
    if (wid == 0) {
        m = (lane < 16) ? wredm[lane] : -1e30f;
        s = (lane < 16) ? wreds[lane] : 0.f;
#pragma unroll
        for (int off = 8; off > 0; off >>= 1) {
            const float m2 = __shfl_down(m, off);
            const float s2 = __shfl_down(s, off);
            const float mn = fmaxf(m, m2);
            s = s * expf(m - mn) + s2 * expf(m2 - mn);
            m = mn;
        }
        if (lane == 0) fin = m + logf(s);
    }
    __syncthreads();
    const float lz = fin;
    for (int i = tid; i < V_; i += 1024) row[i] = us2f(rowb[i]) - lz;
}

// Act head log-softmax: f32 in -> f32 out
__global__ __launch_bounds__(256) void logsoftmax_act_kernel(const float* __restrict__ in,
                                                             float* __restrict__ out)
{
    const float* row = in + (size_t)blockIdx.x * AV_;
    float* orow = out + (size_t)blockIdx.x * AV_;
    const int tid = threadIdx.x;
    __shared__ float red[256];
    float m = -1e30f;
    if (tid < AV_) m = row[tid];
    red[tid] = m;
    __syncthreads();
    for (int off = 128; off > 0; off >>= 1) {
        if (tid < off) red[tid] = fmaxf(red[tid], red[tid + off]);
        __syncthreads();
    }
    m = red[0];
    __syncthreads();
    float s = 0.f;
    if (tid < AV_) s = expf(row[tid] - m);
    red[tid] = s;
    __syncthreads();
    for (int off = 128; off > 0; off >>= 1) {
        if (tid < off) red[tid] += red[tid + off];
        __syncthreads();
    }
    const float lz = m + logf(red[0]);
    if (tid < AV_) orow[tid] = row[tid] - lz;
}

// ---------------------------------------------------------------------------
extern "C" void kernel_launch(void* const* d_in, const int* in_sizes, int n_in,
                              void* d_out, int out_size, void* d_ws, size_t ws_size,
                              hipStream_t stream)
{
    const int* input_edits   = (const int*)d_in[0];
    const int* input_actions = (const int*)d_in[1];
    const int* simp_sent     = (const int*)d_in[2];
    const int* org_ids       = (const int*)d_in[3];
    const float* enc_org     = (const float*)d_in[4];
    const float* emb         = (const float*)d_in[5];
    const float* Wih_e = (const float*)d_in[6];
    const float* Whh_e = (const float*)d_in[7];
    const float* bih_e = (const float*)d_in[8];
    const float* bhh_e = (const float*)d_in[9];
    const float* Wih_a = (const float*)d_in[10];
    const float* Whh_a = (const float*)d_in[11];
    const float* bih_a = (const float*)d_in[12];
    const float* bhh_a = (const float*)d_in[13];
    const float* Wih_w = (const float*)d_in[14];
    const float* Whh_w = (const float*)d_in[15];
    const float* bih_w = (const float*)d_in[16];
    const float* bhh_w = (const float*)d_in[17];
    const float* W_align = (const float*)d_in[18];
    const float* W_proj  = (const float*)d_in[19];
    const float* W_ref   = (const float*)d_in[20];
    const float* b_ref   = (const float*)d_in[21];
    const float* W_mlp   = (const float*)d_in[22];
    const float* b_mlp   = (const float*)d_in[23];
    const float* W_act   = (const float*)d_in[24];
    const float* b_act   = (const float*)d_in[25];
    const float* W_out   = (const float*)d_in[26];
    const float* b_out   = (const float*)d_in[27];
    const float* W_outact = (const float*)d_in[28];
    const float* b_outact = (const float*)d_in[29];
    const float* action_mask = (const float*)d_in[30];

    float* out = (float*)d_out;
    float* edit_out = out;                               // (2032, 30522) f32
    float* act_out  = out + (size_t)R_ * V_;             // (2032, 200)   f32

    // Workspace layout
    char* p = (char*)d_ws;
    auto take = [&](size_t bytes) { void* q = (void*)p; p += ((bytes + 255) / 256) * 256; return q; };
    int* flags = (int*)take(3 * 256);
    unsigned short* hbuf = (unsigned short*)take((size_t)3 * 2 * B_ * H_ * 2);
    char* alias_base = p;                                // xe..pxw region (dead after LSTM)
    bf16* xe   = (bf16*)take((size_t)B_ * T_ * H_ * 2);
    bf16* xa   = (bf16*)take((size_t)B_ * T_ * H_ * 2);
    bf16* xw   = (bf16*)take((size_t)B_ * S_ * H_ * 2);
    bf16* pxe  = (bf16*)take((size_t)B_ * T_ * G4_ * 2);
    bf16* pxa  = (bf16*)take((size_t)B_ * T_ * G4_ * 2);
    bf16* pxw  = (bf16*)take((size_t)B_ * S_ * G4_ * 2);
    bf16* oute = (bf16*)take((size_t)B_ * T_ * H_ * 2);
    bf16* outa = (bf16*)take((size_t)B_ * T_ * H_ * 2);
    bf16* outw = (bf16*)take((size_t)B_ * S_ * H_ * 2);
    bf16* enc  = (bf16*)take((size_t)B_ * L_ * H_ * 2);
    bf16* cw   = (bf16*)take((size_t)R_ * H_ * 2);
    bf16* ced  = (bf16*)take((size_t)R_ * H_ * 2);
    bf16* cac  = (bf16*)take((size_t)R_ * H_ * 2);
    bf16* qb   = (bf16*)take((size_t)R_ * H_ * 2);
    bf16* app  = (bf16*)take((size_t)R_ * H_ * 2);
    bf16* fe   = (bf16*)take((size_t)R_ * K5_ * 2);
    bf16* fa   = (bf16*)take((size_t)R_ * K5_ * 2);
    bf16* he   = (bf16*)take((size_t)R_ * H_ * 2);
    bf16* ha   = (bf16*)take((size_t)R_ * H_ * 2);
    int*  cd   = (int*)take((size_t)R_ * 4);
    int*  ci   = (int*)take((size_t)R_ * 4);
    int*  ca   = (int*)take((size_t)R_ * 4);
    float* actbuf = (float*)take((size_t)R_ * AV_ * 4);
    bf16* Wmlpb = (bf16*)take((size_t)H_ * K5_ * 2);     // 5.9 MB
    bf16* Wactb = (bf16*)take((size_t)H_ * K5_ * 2);     // 5.9 MB
    bf16* Woab  = (bf16*)take((size_t)AV_ * H_ * 2);     // 0.31 MB
    // W_out bf16 aliases xe..pxw (55 MB >= 46.9 MB), converted during LSTM.
    bf16* Wob = (bf16*)alias_base;
    // Wih bf16 copies alias fe (dead until feat).
    bf16* WihEb = fe;
    bf16* WihAb = fe + (size_t)G4_ * H_;
    bf16* WihWb = fe + (size_t)2 * G4_ * H_;
    // enc_org/W_align/W_proj bf16 copies alias fa (dead until feat; used at
    // steps 3 and 8, both before feat at step 10).
    bf16* encb   = fa;
    bf16* Walb   = fa + (size_t)B_ * S_ * H_;
    bf16* Wprojb = fa + (size_t)B_ * S_ * H_ + (size_t)H_ * H_;

    // 0. Zero barrier flags
    hipMemsetAsync(flags, 0, 3 * 256, stream);

    // 0.5 Convert all f32 GEMM operands to bf16 (one pass, 9 matrices)
    ConvJobs jobs;
    jobs.src[0] = Wih_e;   jobs.dst[0] = WihEb;  jobs.n4[0] = G4_ * H_ / 4;
    jobs.src[1] = Wih_a;   jobs.dst[1] = WihAb;  jobs.n4[1] = G4_ * H_ / 4;
    jobs.src[2] = Wih_w;   jobs.dst[2] = WihWb;  jobs.n4[2] = G4_ * H_ / 4;
    jobs.src[3] = W_mlp;   jobs.dst[3] = Wmlpb;  jobs.n4[3] = H_ * K5_ / 4;
    jobs.src[4] = W_act;   jobs.dst[4] = Wactb;  jobs.n4[4] = H_ * K5_ / 4;
    jobs.src[5] = enc_org; jobs.dst[5] = encb;   jobs.n4[5] = B_ * S_ * H_ / 4;
    jobs.src[6] = W_align; jobs.dst[6] = Walb;   jobs.n4[6] = H_ * H_ / 4;
    jobs.src[7] = W_proj;  jobs.dst[7] = Wprojb; jobs.n4[7] = H_ * H_ / 4;
    jobs.src[8] = W_outact;jobs.dst[8] = Woab;   jobs.n4[8] = AV_ * H_ / 4;
    conv_many_kernel<<<dim3((H_ * K5_ / 4 + 255) / 256, 9), 256, 0, stream>>>(jobs);

    // 1. Embedding gathers (fused)
    gather3_kernel<<<dim3(B_ * S_, 3), 256, 0, stream>>>(
        input_edits, input_actions, simp_sent, emb, xe, xa, xw);

    // 2. px = x@Wih^T + bih + bhh
    dim3 gpx((B_ * T_ + 127) / 128, (G4_ + 127) / 128);
    gemm_mfma<<<gpx, 256, 0, stream>>>(xe, WihEb, bih_e, bhh_e, pxe, nullptr, B_ * T_, G4_, H_, 0, 0, H_);
    gemm_mfma<<<gpx, 256, 0, stream>>>(xa, WihAb, bih_a, bhh_a, pxa, nullptr, B_ * T_, G4_, H_, 0, 0, H_);
    dim3 gpxw((B_ * S_ + 127) / 128, (G4_ + 127) / 128);
    gemm_mfma<<<gpxw, 256, 0, stream>>>(xw, WihWb, bih_w, bhh_w, pxw, nullptr, B_ * S_, G4_, H_, 0, 0, H_);

    // 3. enc = tanh(enc_org @ W_align^T)[:, 1:]
    dim3 genc((B_ * L_ + 127) / 128, (H_ + 127) / 128);
    gemm_mfma<<<genc, 256, 0, stream>>>(encb, Walb, nullptr, nullptr, enc, nullptr, B_ * L_, H_, H_, 1, L_, H_);

    // 4. Counters scan
    counters_kernel<<<1, 64, 0, stream>>>(input_edits, org_ids, cd, ci, ca);

    // 5. Persistent cooperative LSTMs + folded W_out->bf16 converter blocks
    lstm_mfma_kernel<<<3 * NB_ + NCV_, 256, 0, stream>>>(pxe, pxa, pxw, Whh_e, Whh_a, Whh_w,
                                                         oute, outa, outw, hbuf, flags,
                                                         W_out, Wob);

    // 6. c_word gather
    gather_cword_kernel<<<R_, 256, 0, stream>>>(outw, ci, cw);

    // 7. wref mixing
    ref_combine_kernel<<<R_, 256, 0, stream>>>(oute, outa, enc, W_ref, b_ref, cd, ca, ced, cac);

    // 8. q = c_word @ W_proj^T
    dim3 gproj((R_ + 127) / 128, (H_ + 127) / 128);
    gemm_mfma<<<gproj, 256, 0, stream>>>(cw, Wprojb, nullptr, nullptr, qb, nullptr, R_, H_, H_, 0, 0, H_);

    // 9. attention
    attn_kernel<<<R_, 256, 0, stream>>>(qb, enc, app);

    // 10. feature concat (overwrites the fe/fa aliases — all dead now)
    feat_kernel<<<R_, 256, 0, stream>>>(oute, outa, app, ced, cac, cw, fe, fa);

    // 11. hidden layers (tanh, K=3840)
    gemm_mfma<<<gproj, 256, 0, stream>>>(fe, Wmlpb, b_mlp, nullptr, he, nullptr, R_, H_, K5_, 1, 0, K5_);
    gemm_mfma<<<gproj, 256, 0, stream>>>(fa, Wactb, b_act, nullptr, ha, nullptr, R_, H_, K5_, 1, 0, K5_);

    // 12. act head + log-softmax
    dim3 gact((R_ + 127) / 128, (AV_ + 127) / 128);
    gemm_mfma<<<gact, 256, 0, stream>>>(ha, Woab, b_outact, action_mask, nullptr, actbuf, R_, AV_, H_, 0, 0, H_);
    logsoftmax_act_kernel<<<R_, 256, 0, stream>>>(actbuf, act_out);

    // 13. edit head (bf16 W) + in-place log-softmax
    dim3 gedit((R_ + 127) / 128, (V_ + 127) / 128);
    gemm_mfma<<<gedit, 256, 0, stream>>>(he, Wob, b_out, nullptr, nullptr, edit_out, R_, V_, H_, 0, 0, H_);
    logsoftmax_edit_kernel<<<R_, 1024, 0, stream>>>(edit_out);
}